// Round 1
// baseline (96.306 us; speedup 1.0000x reference)
//
#include <hip/hip_runtime.h>
#include <hip/hip_bf16.h>
#include <math.h>

#define D_FEAT 64
#define N_ETYPES 8
#define EPS_F 1e-8f

// ---------------------------------------------------------------------------
// Kernel 0: tiny prep — ew_table[t] = sum_j edge_weight[t,j]*edge_weight_param[j] + 1
// and clear the has_zero_node flag (ws is poisoned 0xAA by the harness).
// ---------------------------------------------------------------------------
__global__ void prep_kernel(const float* __restrict__ edge_weight,
                            const float* __restrict__ edge_weight_param,
                            float* __restrict__ ew_table,
                            int* __restrict__ flag) {
    int t = threadIdx.x;
    if (t == 0) *flag = 0;
    if (t < N_ETYPES) {
        float s = 1.0f;
        #pragma unroll
        for (int j = 0; j < N_ETYPES; ++j)
            s += edge_weight[t * N_ETYPES + j] * edge_weight_param[j];
        ew_table[t] = s;
    }
}

// ---------------------------------------------------------------------------
// Kernel 1: per-node pass. 16 lanes per node, float4 per lane (64 floats/row).
//   - out row  = feat row (bit-exact copy; also zero-init for zero rows)
//   - mask[n]  = (sum|feat| == 0) ? 0 : 1
//   - nw_exp[n]= mask * exp(feat . attn)
//   - nw_exp_sum[n] = 0
//   - flag = 1 if any zero row
// ---------------------------------------------------------------------------
__global__ void node_kernel(const float* __restrict__ feat,
                            const float* __restrict__ attn,
                            float* __restrict__ out,
                            float* __restrict__ nw_exp,
                            float* __restrict__ nw_exp_sum,
                            int* __restrict__ mask,
                            int* __restrict__ flag,
                            int N) {
    int gid  = blockIdx.x * blockDim.x + threadIdx.x;
    int node = gid >> 4;          // 16 lanes per node row
    int sub  = gid & 15;          // lane's float4 within the row
    if (node >= N) return;

    const float4 f = ((const float4*)feat)[(size_t)node * 16 + sub];
    const float4 a = ((const float4*)attn)[sub];

    // out = feat (bit-exact; correct final value for all nonzero-mask nodes,
    // and the zero-init of the accumulator for zero-mask nodes)
    ((float4*)out)[(size_t)node * 16 + sub] = f;

    float abss = fabsf(f.x) + fabsf(f.y) + fabsf(f.z) + fabsf(f.w);
    float dot  = f.x * a.x + f.y * a.y + f.z * a.z + f.w * a.w;

    // reduce across the 16-lane group (xor masks < 16 stay inside the group)
    #pragma unroll
    for (int off = 1; off < 16; off <<= 1) {
        abss += __shfl_xor(abss, off);
        dot  += __shfl_xor(dot,  off);
    }

    if (sub == 0) {
        int m = (abss == 0.0f) ? 0 : 1;
        mask[node]       = m;
        nw_exp[node]     = m ? expf(dot) : 0.0f;   // TEMPERATURE == 1
        nw_exp_sum[node] = 0.0f;
        if (m == 0) *flag = 1;   // racy stores of the same value: fine
    }
}

// ---------------------------------------------------------------------------
// Kernel 2: edge pass — only does work if some node row is all-zero.
// Accumulates directly into out[dst] (pre-zeroed by the feat copy).
// ---------------------------------------------------------------------------
__global__ void edge_kernel(const int* __restrict__ src,
                            const int* __restrict__ dst,
                            const int* __restrict__ e_feat,
                            const float* __restrict__ feat,
                            const float* __restrict__ nw_exp,
                            const int* __restrict__ mask,
                            const float* __restrict__ ew_table,
                            const int* __restrict__ flag,
                            float* __restrict__ out,
                            float* __restrict__ nw_exp_sum,
                            int E) {
    if (*flag == 0) return;   // no zero-mask node: nothing to aggregate
    int e = blockIdx.x * blockDim.x + threadIdx.x;
    if (e >= E) return;
    int d = dst[e];
    if (mask[d] != 0) return;  // destination keeps its original features
    int s = src[e];
    float w = nw_exp[s];       // already 0 for zero-mask sources
    atomicAdd(&nw_exp_sum[d], w);
    float scale = w * ew_table[e_feat[e] - 1];
    const float* fs = feat + (size_t)s * D_FEAT;
    float*       od = out  + (size_t)d * D_FEAT;
    #pragma unroll 4
    for (int k = 0; k < D_FEAT; ++k)
        atomicAdd(&od[k], fs[k] * scale);
}

// ---------------------------------------------------------------------------
// Kernel 3: fixup — divide zero-mask rows by denom. Flag-gated.
// ---------------------------------------------------------------------------
__global__ void fixup_kernel(float* __restrict__ out,
                             const float* __restrict__ nw_exp_sum,
                             const int* __restrict__ mask,
                             const int* __restrict__ flag,
                             int N) {
    if (*flag == 0) return;
    int n = blockIdx.x * blockDim.x + threadIdx.x;
    if (n >= N || mask[n] != 0) return;
    float s = nw_exp_sum[n];
    float denom = (s < EPS_F) ? 1.0f : s;
    float* row = out + (size_t)n * D_FEAT;
    #pragma unroll 4
    for (int k = 0; k < D_FEAT; ++k)
        row[k] = row[k] / denom;
}

extern "C" void kernel_launch(void* const* d_in, const int* in_sizes, int n_in,
                              void* d_out, int out_size, void* d_ws, size_t ws_size,
                              hipStream_t stream) {
    const float* feat              = (const float*)d_in[0];
    const float* attn              = (const float*)d_in[1];
    const float* edge_weight       = (const float*)d_in[2];
    const float* edge_weight_param = (const float*)d_in[3];
    const int*   src               = (const int*)d_in[4];
    const int*   dst               = (const int*)d_in[5];
    const int*   e_feat            = (const int*)d_in[6];
    float*       out               = (float*)d_out;

    const int N = in_sizes[0] / D_FEAT;
    const int E = in_sizes[4];

    // workspace layout (~1.2 MB): nw_exp[N] | nw_exp_sum[N] | mask[N] | ew_table[8] | flag
    float* nw_exp     = (float*)d_ws;
    float* nw_exp_sum = nw_exp + N;
    int*   mask       = (int*)(nw_exp_sum + N);
    float* ew_table   = (float*)(mask + N);
    int*   flag       = (int*)(ew_table + N_ETYPES);

    prep_kernel<<<1, 64, 0, stream>>>(edge_weight, edge_weight_param, ew_table, flag);

    const int threadsA = 256;
    const int nodesPerBlock = threadsA / 16;
    node_kernel<<<(N + nodesPerBlock - 1) / nodesPerBlock, threadsA, 0, stream>>>(
        feat, attn, out, nw_exp, nw_exp_sum, mask, flag, N);

    edge_kernel<<<(E + 255) / 256, 256, 0, stream>>>(
        src, dst, e_feat, feat, nw_exp, mask, ew_table, flag, out, nw_exp_sum, E);

    fixup_kernel<<<(N + 255) / 256, 256, 0, stream>>>(
        out, nw_exp_sum, mask, flag, N);
}